// Round 1
// baseline (619.833 us; speedup 1.0000x reference)
//
#include <hip/hip_runtime.h>
#include <hip/hip_bf16.h>
#include <hip/hip_fp16.h>

typedef _Float16 f16;
typedef _Float16 f16x8 __attribute__((ext_vector_type(8)));
typedef _Float16 f16x4 __attribute__((ext_vector_type(4)));
typedef float f32x4 __attribute__((ext_vector_type(4)));

#define D_MODEL 768
#define S_CTX   4096
#define NBATCH  2
#define M_TOK   (NBATCH * S_CTX)   // 8192
#define N3      (3 * D_MODEL)      // 2304

// ---------------------------------------------------------------- utilities
__device__ __forceinline__ void gload_lds16(const void* g, void* l) {
  // async global->LDS, 16B per lane; LDS dest = wave-uniform base + lane*16
  __builtin_amdgcn_global_load_lds(
      (__attribute__((address_space(1))) unsigned int*)g,
      (__attribute__((address_space(3))) unsigned int*)l, 16, 0, 0);
}

// ---------------------------------------------------------------- fp32->fp16
__global__ __launch_bounds__(256) void cvt_f32_f16(const float* __restrict__ s,
                                                   f16* __restrict__ d, int n4) {
  int i = blockIdx.x * 256 + threadIdx.x;
  if (i >= n4) return;
  f32x4 v = ((const f32x4*)s)[i];
  f16x4 h;
  h[0] = (f16)v[0]; h[1] = (f16)v[1]; h[2] = (f16)v[2]; h[3] = (f16)v[3];
  ((f16x4*)d)[i] = h;
}

// ---------------------------------------------------------------- projection
// qkv[m,n] = sum_k x[m,k] * W[n,k];  M=8192, N=2304, K=768
// n<768 -> Q row-major; 768..1535 -> K row-major; >=1536 -> V stored transposed
__global__ __launch_bounds__(256, 2) void proj_gemm(
    const f16* __restrict__ A, const f16* __restrict__ B,
    f16* __restrict__ qh, f16* __restrict__ kh, f16* __restrict__ vth) {
  __shared__ f16 As[128 * 32];
  __shared__ f16 Bs[128 * 32];

  const int tid  = threadIdx.x;
  const int w    = tid >> 6, lane = tid & 63;
  const int wr   = w >> 1,   wc   = w & 1;
  const int bm0  = blockIdx.x * 128, bn0 = blockIdx.y * 128;
  const int srow = lane >> 2;          // row within 16-row chunk
  const int scol = (lane & 3) * 8;     // k-offset within 32

  f32x4 acc[4][4] = {};

  const f16* gA = A + (size_t)bm0 * 768;
  const f16* gB = B + (size_t)bn0 * 768;

  for (int kt = 0; kt < 24; ++kt) {
    __syncthreads();
    const int k0 = kt * 32 + scol;
#pragma unroll
    for (int cc = 0; cc < 2; ++cc) {
      int c = w + cc * 4;                       // chunk 0..7 (16 rows each)
      gload_lds16(gA + (size_t)(c * 16 + srow) * 768 + k0, (char*)As + c * 1024);
      gload_lds16(gB + (size_t)(c * 16 + srow) * 768 + k0, (char*)Bs + c * 1024);
    }
    __syncthreads();

    const int fr = lane & 15, fk = (lane >> 4) * 8;
    f16x8 af[4], bf[4];
#pragma unroll
    for (int i = 0; i < 4; ++i)
      af[i] = *(const f16x8*)(As + (wr * 64 + i * 16 + fr) * 32 + fk);
#pragma unroll
    for (int j = 0; j < 4; ++j)
      bf[j] = *(const f16x8*)(Bs + (wc * 64 + j * 16 + fr) * 32 + fk);
#pragma unroll
    for (int i = 0; i < 4; ++i)
#pragma unroll
      for (int j = 0; j < 4; ++j)
        acc[i][j] = __builtin_amdgcn_mfma_f32_16x16x32_f16(af[i], bf[j], acc[i][j], 0, 0, 0);
  }

  const int fr = lane & 15, fq = lane >> 4;
#pragma unroll
  for (int i = 0; i < 4; ++i) {
#pragma unroll
    for (int j = 0; j < 4; ++j) {
      int gn      = bn0 + wc * 64 + j * 16 + fr;
      int gm_base = bm0 + wr * 64 + i * 16 + fq * 4;
      if (gn < 1536) {
        f16* dst = (gn < 768) ? qh : kh;
        int  col = (gn < 768) ? gn : gn - 768;
#pragma unroll
        for (int r = 0; r < 4; ++r)
          dst[(size_t)(gm_base + r) * 768 + col] = (f16)acc[i][j][r];
      } else {
        int d = gn - 1536;
        int bb = gm_base >> 12, s = gm_base & 4095;
        f16x4 h;
        h[0] = (f16)acc[i][j][0]; h[1] = (f16)acc[i][j][1];
        h[2] = (f16)acc[i][j][2]; h[3] = (f16)acc[i][j][3];
        *(f16x4*)(vth + ((size_t)bb * 768 + d) * 4096 + s) = h;  // 4 consecutive s
      }
    }
  }
}

// ---------------------------------------------------------------- attention
// 1 WG = (batch, 32-row q-block). 4 waves. KV block 64.
// wave w: QK^T col-tile w (16 keys), PV cols [w*192, w*192+192)
__global__ __launch_bounds__(256, 1) void attn(
    const f16* __restrict__ qg, const f16* __restrict__ kg,
    const f16* __restrict__ vt, const float* __restrict__ x,
    float* __restrict__ out) {
  __shared__ __align__(16) char  Qs[32 * 1536];   // swizzled f16 [32][768]
  __shared__ __align__(16) float Ss[32 * 64];
  __shared__ __align__(16) char  Ps[32 * 128];    // swizzled f16 [32][64]
  __shared__ __align__(16) float mS[32], lS[32], fS[32];

  const int tid = threadIdx.x;
  const int w = tid >> 6, lane = tid & 63;
  const int fr = lane & 15, fq = lane >> 4;

  const int u  = blockIdx.x;
  const int b  = u & 1;
  const int qb = 127 - (u >> 1);          // heavy q-blocks first
  const int q0 = qb * 32;

  const f16* qrow = qg + ((size_t)b * 4096 + q0) * 768;
  const f16* kb_  = kg + (size_t)b * 4096 * 768;
  const f16* vb_  = vt + (size_t)b * 768 * 4096;

  // stage Q into LDS, XOR-swizzled (row stride 1536B would be 32-way conflict)
#pragma unroll
  for (int it = 0; it < 12; ++it) {
    int c   = it * 256 + tid;             // 0..3071, 96 16B-chunks per row
    int row = c / 96, ch = c % 96;
    uint4 v = *(const uint4*)(qrow + (size_t)row * 768 + ch * 8);
    int byte = row * 1536 + ch * 16;
    byte ^= ((row & 7) << 4);
    *(uint4*)(Qs + byte) = v;
  }
  if (tid < 32) { mS[tid] = -1e30f; lS[tid] = 0.f; }
  __syncthreads();

  f32x4 acc[2][12] = {};

  const int nsteps = (q0 + 32 + 63) >> 6;
  for (int t = 0; t < nsteps; ++t) {
    const int kv0 = t * 64;

    // ---- phase 1: QK^T  (keys kv0 + w*16 + fr)
    f32x4 sc0 = {}, sc1 = {};
    const f16* kp = kb_ + (size_t)(kv0 + w * 16 + fr) * 768 + fq * 8;
#pragma unroll
    for (int kk = 0; kk < 24; ++kk) {
      f16x8 bfr = *(const f16x8*)(kp + kk * 32);
      int by0 = fr * 1536 + (kk * 32 + fq * 8) * 2;
      f16x8 a0 = *(const f16x8*)(Qs + (by0 ^ ((fr & 7) << 4)));
      int rb  = 16 + fr;
      int by1 = rb * 1536 + (kk * 32 + fq * 8) * 2;
      f16x8 a1 = *(const f16x8*)(Qs + (by1 ^ ((rb & 7) << 4)));
      sc0 = __builtin_amdgcn_mfma_f32_16x16x32_f16(a0, bfr, sc0, 0, 0, 0);
      sc1 = __builtin_amdgcn_mfma_f32_16x16x32_f16(a1, bfr, sc1, 0, 0, 0);
    }
    {
      const int colk = w * 16 + fr;
      const int gkey = kv0 + colk;
#pragma unroll
      for (int r = 0; r < 4; ++r) {
        int row0 = fq * 4 + r;
        Ss[row0 * 64 + colk] = (gkey > q0 + row0) ? -1e30f : sc0[r];
        int row1 = 16 + fq * 4 + r;
        Ss[row1 * 64 + colk] = (gkey > q0 + row1) ? -1e30f : sc1[r];
      }
    }
    __syncthreads();

    // ---- phase 2: online softmax, 8 threads per row
    {
      const int row = tid >> 3, sub = tid & 7;
      f32x4 s0 = *(const f32x4*)(Ss + row * 64 + sub * 8);
      f32x4 s1 = *(const f32x4*)(Ss + row * 64 + sub * 8 + 4);
      float mx = fmaxf(fmaxf(fmaxf(s0[0], s0[1]), fmaxf(s0[2], s0[3])),
                       fmaxf(fmaxf(s1[0], s1[1]), fmaxf(s1[2], s1[3])));
      mx = fmaxf(mx, __shfl_xor(mx, 1));
      mx = fmaxf(mx, __shfl_xor(mx, 2));
      mx = fmaxf(mx, __shfl_xor(mx, 4));
      float mo = mS[row];
      float mn = fmaxf(mo, mx);
      float f  = __expf(mo - mn);
      float p[8];
#pragma unroll
      for (int i = 0; i < 4; ++i) p[i]     = __expf(s0[i] - mn);
#pragma unroll
      for (int i = 0; i < 4; ++i) p[4 + i] = __expf(s1[i] - mn);
      float sum = 0.f;
#pragma unroll
      for (int i = 0; i < 8; ++i) sum += p[i];
      sum += __shfl_xor(sum, 1);
      sum += __shfl_xor(sum, 2);
      sum += __shfl_xor(sum, 4);
      if (sub == 0) { mS[row] = mn; fS[row] = f; lS[row] = lS[row] * f + sum; }
      f16x8 ph;
#pragma unroll
      for (int i = 0; i < 8; ++i) ph[i] = (f16)p[i];
      int byte = row * 128 + sub * 16;
      byte ^= ((row & 7) << 4);
      *(f16x8*)(Ps + byte) = ph;
    }
    __syncthreads();

    // ---- phase 3: rescale + PV
    {
      f32x4 f0 = *(const f32x4*)(fS + fq * 4);
      f32x4 f1 = *(const f32x4*)(fS + 16 + fq * 4);
#pragma unroll
      for (int ct = 0; ct < 12; ++ct)
#pragma unroll
        for (int r = 0; r < 4; ++r) {
          acc[0][ct][r] *= f0[r];
          acc[1][ct][r] *= f1[r];
        }
#pragma unroll
      for (int ks = 0; ks < 2; ++ks) {
        int byA0 = fr * 128 + (ks * 32 + fq * 8) * 2;
        f16x8 pa0 = *(const f16x8*)(Ps + (byA0 ^ ((fr & 7) << 4)));
        int rb   = 16 + fr;
        int byA1 = rb * 128 + (ks * 32 + fq * 8) * 2;
        f16x8 pa1 = *(const f16x8*)(Ps + (byA1 ^ ((rb & 7) << 4)));
        const f16* vp = vb_ + (size_t)(w * 192 + fr) * 4096 + kv0 + ks * 32 + fq * 8;
#pragma unroll
        for (int ct = 0; ct < 12; ++ct) {
          f16x8 bv = *(const f16x8*)(vp + (size_t)ct * 16 * 4096);
          acc[0][ct] = __builtin_amdgcn_mfma_f32_16x16x32_f16(pa0, bv, acc[0][ct], 0, 0, 0);
          acc[1][ct] = __builtin_amdgcn_mfma_f32_16x16x32_f16(pa1, bv, acc[1][ct], 0, 0, 0);
        }
      }
    }
    // no barrier needed here: next phase-1 doesn't touch Ps/Ss hazards
  }

  // ---- epilogue: out = x + acc / l
  {
    f32x4 l0 = *(const f32x4*)(lS + fq * 4);
    f32x4 l1 = *(const f32x4*)(lS + 16 + fq * 4);
    f32x4 i0, i1;
#pragma unroll
    for (int r = 0; r < 4; ++r) { i0[r] = 1.f / l0[r]; i1[r] = 1.f / l1[r]; }
    const size_t obase = (size_t)b * 4096 + q0;
#pragma unroll
    for (int ct = 0; ct < 12; ++ct) {
      int d = w * 192 + ct * 16 + fr;
#pragma unroll
      for (int r = 0; r < 4; ++r) {
        {
          int row = fq * 4 + r;
          size_t idx = (obase + row) * 768 + d;
          out[idx] = x[idx] + acc[0][ct][r] * i0[r];
        }
        {
          int row = 16 + fq * 4 + r;
          size_t idx = (obase + row) * 768 + d;
          out[idx] = x[idx] + acc[1][ct][r] * i1[r];
        }
      }
    }
  }
}

// ---------------------------------------------------------------- launch
extern "C" void kernel_launch(void* const* d_in, const int* in_sizes, int n_in,
                              void* d_out, int out_size, void* d_ws, size_t ws_size,
                              hipStream_t stream) {
  const float* x  = (const float*)d_in[0];   // [2,4096,768] f32
  const float* Wp = (const float*)d_in[1];   // [2304,768] f32
  float* out = (float*)d_out;

  char* ws = (char*)d_ws;
  f16* x_h  = (f16*)(ws);                    // 12,582,912 B
  f16* w_h  = (f16*)(ws + 12582912);         //  3,538,944 B
  f16* q_h  = (f16*)(ws + 16121856);         // 12,582,912 B
  f16* k_h  = (f16*)(ws + 28704768);         // 12,582,912 B
  f16* vt_h = (f16*)(ws + 41287680);         // 12,582,912 B  (total ~51.4 MiB)

  cvt_f32_f16<<<(M_TOK * D_MODEL) / 1024, 256, 0, stream>>>(x, x_h, (M_TOK * D_MODEL) / 4);
  cvt_f32_f16<<<(N3 * D_MODEL) / 1024, 256, 0, stream>>>(Wp, w_h, (N3 * D_MODEL) / 4);
  proj_gemm<<<dim3(64, 18), 256, 0, stream>>>(x_h, w_h, q_h, k_h, vt_h);
  attn<<<256, 256, 0, stream>>>(q_h, k_h, vt_h, x, out);
}

// Round 2
// 416.033 us; speedup vs baseline: 1.4899x; 1.4899x over previous
//
#include <hip/hip_runtime.h>
#include <hip/hip_bf16.h>
#include <hip/hip_fp16.h>

typedef _Float16 f16;
typedef _Float16 f16x8 __attribute__((ext_vector_type(8)));
typedef _Float16 f16x4 __attribute__((ext_vector_type(4)));
typedef float f32x4 __attribute__((ext_vector_type(4)));

#define D_MODEL 768
#define S_CTX   4096
#define NBATCH  2
#define M_TOK   (NBATCH * S_CTX)   // 8192
#define N3      (3 * D_MODEL)      // 2304

// ---------------------------------------------------------------- utilities
__device__ __forceinline__ void gload_lds16(const void* g, void* l) {
  __builtin_amdgcn_global_load_lds(
      (__attribute__((address_space(1))) unsigned int*)g,
      (__attribute__((address_space(3))) unsigned int*)l, 16, 0, 0);
}

// ---------------------------------------------------------------- fp32->fp16
__global__ __launch_bounds__(256) void cvt_f32_f16(const float* __restrict__ s,
                                                   f16* __restrict__ d, int n4) {
  int i = blockIdx.x * 256 + threadIdx.x;
  if (i >= n4) return;
  f32x4 v = ((const f32x4*)s)[i];
  f16x4 h;
  h[0] = (f16)v[0]; h[1] = (f16)v[1]; h[2] = (f16)v[2]; h[3] = (f16)v[3];
  ((f16x4*)d)[i] = h;
}

// ---------------------------------------------------------------- projection
// qkv[m,n] = sum_k x[m,k]*W[n,k]; n<768 -> Q, 768..1535 -> K, >=1536 -> V^T
__global__ __launch_bounds__(256, 2) void proj_gemm(
    const f16* __restrict__ A, const f16* __restrict__ B,
    f16* __restrict__ qh, f16* __restrict__ kh, f16* __restrict__ vth) {
  __shared__ f16 As[128 * 32];
  __shared__ f16 Bs[128 * 32];

  const int tid  = threadIdx.x;
  const int w    = tid >> 6, lane = tid & 63;
  const int wr   = w >> 1,   wc   = w & 1;
  const int bm0  = blockIdx.x * 128, bn0 = blockIdx.y * 128;
  const int srow = lane >> 2;
  const int scol = (lane & 3) * 8;

  f32x4 acc[4][4] = {};

  const f16* gA = A + (size_t)bm0 * 768;
  const f16* gB = B + (size_t)bn0 * 768;

  for (int kt = 0; kt < 24; ++kt) {
    __syncthreads();
    const int k0 = kt * 32 + scol;
#pragma unroll
    for (int cc = 0; cc < 2; ++cc) {
      int c = w + cc * 4;
      gload_lds16(gA + (size_t)(c * 16 + srow) * 768 + k0, (char*)As + c * 1024);
      gload_lds16(gB + (size_t)(c * 16 + srow) * 768 + k0, (char*)Bs + c * 1024);
    }
    __syncthreads();

    const int fr = lane & 15, fk = (lane >> 4) * 8;
    f16x8 af[4], bf[4];
#pragma unroll
    for (int i = 0; i < 4; ++i)
      af[i] = *(const f16x8*)(As + (wr * 64 + i * 16 + fr) * 32 + fk);
#pragma unroll
    for (int j = 0; j < 4; ++j)
      bf[j] = *(const f16x8*)(Bs + (wc * 64 + j * 16 + fr) * 32 + fk);
#pragma unroll
    for (int i = 0; i < 4; ++i)
#pragma unroll
      for (int j = 0; j < 4; ++j)
        acc[i][j] = __builtin_amdgcn_mfma_f32_16x16x32_f16(af[i], bf[j], acc[i][j], 0, 0, 0);
  }

  const int fr = lane & 15, fq = lane >> 4;
#pragma unroll
  for (int i = 0; i < 4; ++i) {
#pragma unroll
    for (int j = 0; j < 4; ++j) {
      int gn      = bn0 + wc * 64 + j * 16 + fr;
      int gm_base = bm0 + wr * 64 + i * 16 + fq * 4;
      if (gn < 1536) {
        f16* dst = (gn < 768) ? qh : kh;
        int  col = (gn < 768) ? gn : gn - 768;
#pragma unroll
        for (int r = 0; r < 4; ++r)
          dst[(size_t)(gm_base + r) * 768 + col] = (f16)acc[i][j][r];
      } else {
        int d = gn - 1536;
        int bb = gm_base >> 12, s = gm_base & 4095;
        f16x4 h;
        h[0] = (f16)acc[i][j][0]; h[1] = (f16)acc[i][j][1];
        h[2] = (f16)acc[i][j][2]; h[3] = (f16)acc[i][j][3];
        *(f16x4*)(vth + ((size_t)bb * 768 + d) * 4096 + s) = h;
      }
    }
  }
}

// ---------------------------------------------------------------- attention
// grid 512: unit = (batch, 32-row q-block, kv-half). 4 waves, KV step 64.
// Writes UNNORMALIZED partial acc + (m,l). chunk0 -> p0 (f16), chunk1 -> p1 (f32).
#define SS_LD 68
__global__ __launch_bounds__(256, 2) void attn_part(
    const f16* __restrict__ qg, const f16* __restrict__ kg,
    const f16* __restrict__ vt, f16* __restrict__ p0,
    float* __restrict__ p1, float* __restrict__ ml) {
  __shared__ __align__(16) char  Qs[32 * 1536];      // swizzled f16 [32][768]
  __shared__ __align__(16) float Ss[32 * SS_LD];
  __shared__ __align__(16) char  Ps[32 * 128];       // swizzled f16 [32][64]
  __shared__ __align__(16) float mS[32], lS[32], fS[32];

  const int tid = threadIdx.x;
  const int w = tid >> 6, lane = tid & 63;
  const int fr = lane & 15, fq = lane >> 4;

  // heavy chunks first (u<256: qb 127..64), then light reversed (qb 0..63)
  // so CU slot pairs (u, u+256) sum to ~constant work.
  const int u  = blockIdx.x;
  const int v  = (u < 256) ? u : 511 - (u - 256);
  const int qb = 127 - (v >> 2);
  const int b  = (v >> 1) & 1;
  const int c  = v & 1;
  const int q0 = qb * 32;
  const int n  = (q0 + 95) >> 6;     // total KV steps for this q-block
  const int n0 = (n + 1) >> 1;
  const int ts = c ? n0 : 0;
  const int te = c ? n  : n0;

  const f16* qrow = qg + ((size_t)b * 4096 + q0) * 768;
  const f16* kb_  = kg + (size_t)b * 4096 * 768;
  const f16* vb_  = vt + (size_t)b * 768 * 4096;

  // stage Q into LDS, XOR-swizzled
#pragma unroll
  for (int it = 0; it < 12; ++it) {
    int cgl = it * 256 + tid;
    int row = cgl / 96, ch = cgl % 96;
    uint4 qv = *(const uint4*)(qrow + (size_t)row * 768 + ch * 8);
    int byte = row * 1536 + ch * 16;
    byte ^= ((row & 7) << 4);
    *(uint4*)(Qs + byte) = qv;
  }
  if (tid < 32) { mS[tid] = -1e30f; lS[tid] = 0.f; }
  __syncthreads();

  f32x4 acc[2][12] = {};

  for (int t = ts; t < te; ++t) {
    const int kv0 = t * 64;

    // ---- K fragments -> registers (all issued before MFMA chain)
    f16x8 kreg[24];
    const f16* kp = kb_ + (size_t)(kv0 + w * 16 + fr) * 768 + fq * 8;
#pragma unroll
    for (int kk = 0; kk < 24; ++kk) kreg[kk] = *(const f16x8*)(kp + kk * 32);

    // ---- QK^T
    f32x4 sc0 = {}, sc1 = {};
    __builtin_amdgcn_s_setprio(1);
#pragma unroll
    for (int kk = 0; kk < 24; ++kk) {
      int by0 = fr * 1536 + (kk * 32 + fq * 8) * 2;
      f16x8 a0 = *(const f16x8*)(Qs + (by0 ^ ((fr & 7) << 4)));
      int rb  = 16 + fr;
      int by1 = rb * 1536 + (kk * 32 + fq * 8) * 2;
      f16x8 a1 = *(const f16x8*)(Qs + (by1 ^ ((rb & 7) << 4)));
      sc0 = __builtin_amdgcn_mfma_f32_16x16x32_f16(a0, kreg[kk], sc0, 0, 0, 0);
      sc1 = __builtin_amdgcn_mfma_f32_16x16x32_f16(a1, kreg[kk], sc1, 0, 0, 0);
    }
    __builtin_amdgcn_s_setprio(0);
    {
      const int colk = w * 16 + fr;
      const int gkey = kv0 + colk;
#pragma unroll
      for (int r = 0; r < 4; ++r) {
        int row0 = fq * 4 + r;
        Ss[row0 * SS_LD + colk] = (gkey > q0 + row0) ? -1e30f : sc0[r];
        int row1 = 16 + fq * 4 + r;
        Ss[row1 * SS_LD + colk] = (gkey > q0 + row1) ? -1e30f : sc1[r];
      }
    }
    __syncthreads();

    // ---- V fragments -> registers (issued early; overlap softmax)
    f16x8 vreg[24];
    const f16* vp = vb_ + (size_t)(w * 192 + fr) * 4096 + kv0 + fq * 8;
#pragma unroll
    for (int ks = 0; ks < 2; ++ks)
#pragma unroll
      for (int ct = 0; ct < 12; ++ct)
        vreg[ks * 12 + ct] = *(const f16x8*)(vp + ks * 32 + (size_t)ct * 16 * 4096);

    // ---- online softmax, 8 threads per row
    {
      const int row = tid >> 3, sub = tid & 7;
      f32x4 s0 = *(const f32x4*)(Ss + row * SS_LD + sub * 8);
      f32x4 s1 = *(const f32x4*)(Ss + row * SS_LD + sub * 8 + 4);
      float mx = fmaxf(fmaxf(fmaxf(s0[0], s0[1]), fmaxf(s0[2], s0[3])),
                       fmaxf(fmaxf(s1[0], s1[1]), fmaxf(s1[2], s1[3])));
      mx = fmaxf(mx, __shfl_xor(mx, 1));
      mx = fmaxf(mx, __shfl_xor(mx, 2));
      mx = fmaxf(mx, __shfl_xor(mx, 4));
      float mo = mS[row];
      float mn = fmaxf(mo, mx);
      float f  = __expf(mo - mn);
      float p[8];
#pragma unroll
      for (int i = 0; i < 4; ++i) p[i]     = __expf(s0[i] - mn);
#pragma unroll
      for (int i = 0; i < 4; ++i) p[4 + i] = __expf(s1[i] - mn);
      float sum = 0.f;
#pragma unroll
      for (int i = 0; i < 8; ++i) sum += p[i];
      sum += __shfl_xor(sum, 1);
      sum += __shfl_xor(sum, 2);
      sum += __shfl_xor(sum, 4);
      if (sub == 0) { mS[row] = mn; fS[row] = f; lS[row] = lS[row] * f + sum; }
      f16x8 ph;
#pragma unroll
      for (int i = 0; i < 8; ++i) ph[i] = (f16)p[i];
      int byte = row * 128 + sub * 16;
      byte ^= ((row & 7) << 4);
      *(f16x8*)(Ps + byte) = ph;
    }
    __syncthreads();

    // ---- rescale + PV
    {
      f32x4 f0 = *(const f32x4*)(fS + fq * 4);
      f32x4 f1 = *(const f32x4*)(fS + 16 + fq * 4);
#pragma unroll
      for (int ct = 0; ct < 12; ++ct)
#pragma unroll
        for (int r = 0; r < 4; ++r) {
          acc[0][ct][r] *= f0[r];
          acc[1][ct][r] *= f1[r];
        }
      __builtin_amdgcn_s_setprio(1);
#pragma unroll
      for (int ks = 0; ks < 2; ++ks) {
        int byA0 = fr * 128 + (ks * 32 + fq * 8) * 2;
        f16x8 pa0 = *(const f16x8*)(Ps + (byA0 ^ ((fr & 7) << 4)));
        int rb   = 16 + fr;
        int byA1 = rb * 128 + (ks * 32 + fq * 8) * 2;
        f16x8 pa1 = *(const f16x8*)(Ps + (byA1 ^ ((rb & 7) << 4)));
#pragma unroll
        for (int ct = 0; ct < 12; ++ct) {
          acc[0][ct] = __builtin_amdgcn_mfma_f32_16x16x32_f16(pa0, vreg[ks * 12 + ct], acc[0][ct], 0, 0, 0);
          acc[1][ct] = __builtin_amdgcn_mfma_f32_16x16x32_f16(pa1, vreg[ks * 12 + ct], acc[1][ct], 0, 0, 0);
        }
      }
      __builtin_amdgcn_s_setprio(0);
    }
  }

  // ---- epilogue: write UNNORMALIZED partial + (m,l)
  const size_t obase = (size_t)b * 4096 + q0;
  if (c == 0) {
#pragma unroll
    for (int ct = 0; ct < 12; ++ct) {
      int d = w * 192 + ct * 16 + fr;
#pragma unroll
      for (int r = 0; r < 4; ++r) {
        p0[(obase + fq * 4 + r) * 768 + d]      = (f16)acc[0][ct][r];
        p0[(obase + 16 + fq * 4 + r) * 768 + d] = (f16)acc[1][ct][r];
      }
    }
  } else {
#pragma unroll
    for (int ct = 0; ct < 12; ++ct) {
      int d = w * 192 + ct * 16 + fr;
#pragma unroll
      for (int r = 0; r < 4; ++r) {
        p1[(obase + fq * 4 + r) * 768 + d]      = acc[0][ct][r];
        p1[(obase + 16 + fq * 4 + r) * 768 + d] = acc[1][ct][r];
      }
    }
  }
  if (tid < 32) {
    float* mlp = ml + ((size_t)(c * 2 + b) * 4096 + q0 + tid) * 2;
    mlp[0] = mS[tid];
    mlp[1] = lS[tid];
  }
}

// ---------------------------------------------------------------- combine
// out = x + (p0*e^{m0-m} + p1*e^{m1-m}) / (l0*e^{m0-m} + l1*e^{m1-m}); p1 == out
__global__ __launch_bounds__(256) void attn_combine(
    const float* __restrict__ x, const f16* __restrict__ p0,
    const float* __restrict__ ml, float* __restrict__ out) {
  int i = blockIdx.x * 256 + threadIdx.x;        // f32x4 index
  int row = i / 192;                             // 768/4 = 192 vecs per row
  int b = row >> 12, s = row & 4095;
  const float* m0p = ml + ((size_t)b * 4096 + s) * 2;
  const float* m1p = ml + ((size_t)(2 + b) * 4096 + s) * 2;
  float m0 = m0p[0], l0 = m0p[1];
  float m1 = m1p[0], l1 = m1p[1];
  float m  = fmaxf(m0, m1);
  float f0 = __expf(m0 - m), f1 = __expf(m1 - m);
  float inv = 1.f / (l0 * f0 + l1 * f1);
  f32x4 a1 = ((const f32x4*)out)[i];
  f16x4 a0 = ((const f16x4*)p0)[i];
  f32x4 xv = ((const f32x4*)x)[i];
  f32x4 o;
#pragma unroll
  for (int r = 0; r < 4; ++r)
    o[r] = xv[r] + ((float)a0[r] * f0 + a1[r] * f1) * inv;
  ((f32x4*)out)[i] = o;
}

// ---------------------------------------------------------------- launch
extern "C" void kernel_launch(void* const* d_in, const int* in_sizes, int n_in,
                              void* d_out, int out_size, void* d_ws, size_t ws_size,
                              hipStream_t stream) {
  const float* x  = (const float*)d_in[0];   // [2,4096,768] f32
  const float* Wp = (const float*)d_in[1];   // [2304,768] f32
  float* out = (float*)d_out;

  char* ws = (char*)d_ws;
  f16* x_h  = (f16*)(ws);                    // 12,582,912 B (reused as p0 after proj)
  f16* w_h  = (f16*)(ws + 12582912);         //  3,538,944 B (reused as ml after proj)
  f16* q_h  = (f16*)(ws + 16121856);
  f16* k_h  = (f16*)(ws + 28704768);
  f16* vt_h = (f16*)(ws + 41287680);         // total ~51.4 MiB

  f16*   p0 = x_h;
  float* ml = (float*)w_h;

  cvt_f32_f16<<<(M_TOK * D_MODEL) / 1024, 256, 0, stream>>>(x, x_h, (M_TOK * D_MODEL) / 4);
  cvt_f32_f16<<<(N3 * D_MODEL) / 1024, 256, 0, stream>>>(Wp, w_h, (N3 * D_MODEL) / 4);
  proj_gemm<<<dim3(64, 18), 256, 0, stream>>>(x_h, w_h, q_h, k_h, vt_h);
  attn_part<<<512, 256, 0, stream>>>(q_h, k_h, vt_h, p0, out, ml);
  attn_combine<<<(M_TOK * D_MODEL) / 1024, 256, 0, stream>>>(x, p0, ml, out);
}

// Round 3
// 240.178 us; speedup vs baseline: 2.5807x; 1.7322x over previous
//
#include <hip/hip_runtime.h>
#include <hip/hip_bf16.h>
#include <hip/hip_fp16.h>

typedef _Float16 f16;
typedef _Float16 f16x8 __attribute__((ext_vector_type(8)));
typedef _Float16 f16x4 __attribute__((ext_vector_type(4)));
typedef _Float16 f16x2 __attribute__((ext_vector_type(2)));
typedef float f32x4 __attribute__((ext_vector_type(4)));

#define D_MODEL 768
#define S_CTX   4096
#define NBATCH  2
#define M_TOK   (NBATCH * S_CTX)   // 8192
#define N3      (3 * D_MODEL)      // 2304

// ---------------------------------------------------------------- utilities
__device__ __forceinline__ void gload_lds16(const void* g, void* l) {
  __builtin_amdgcn_global_load_lds(
      (__attribute__((address_space(1))) unsigned int*)g,
      (__attribute__((address_space(3))) unsigned int*)l, 16, 0, 0);
}

// ---------------------------------------------------------------- fp32->fp16
__global__ __launch_bounds__(256) void cvt_f32_f16(const float* __restrict__ s,
                                                   f16* __restrict__ d, int n4) {
  int i = blockIdx.x * 256 + threadIdx.x;
  if (i >= n4) return;
  f32x4 v = ((const f32x4*)s)[i];
  f16x4 h;
  h[0] = (f16)v[0]; h[1] = (f16)v[1]; h[2] = (f16)v[2]; h[3] = (f16)v[3];
  ((f16x4*)d)[i] = h;
}

// ---------------------------------------------------------------- projection
__global__ __launch_bounds__(256, 2) void proj_gemm(
    const f16* __restrict__ A, const f16* __restrict__ B,
    f16* __restrict__ qh, f16* __restrict__ kh, f16* __restrict__ vth) {
  __shared__ f16 As[128 * 32];
  __shared__ f16 Bs[128 * 32];

  const int tid  = threadIdx.x;
  const int w    = tid >> 6, lane = tid & 63;
  const int wr   = w >> 1,   wc   = w & 1;
  const int bm0  = blockIdx.x * 128, bn0 = blockIdx.y * 128;
  const int srow = lane >> 2;
  const int scol = (lane & 3) * 8;

  f32x4 acc[4][4] = {};

  const f16* gA = A + (size_t)bm0 * 768;
  const f16* gB = B + (size_t)bn0 * 768;

  for (int kt = 0; kt < 24; ++kt) {
    __syncthreads();
    const int k0 = kt * 32 + scol;
#pragma unroll
    for (int cc = 0; cc < 2; ++cc) {
      int c = w + cc * 4;
      gload_lds16(gA + (size_t)(c * 16 + srow) * 768 + k0, (char*)As + c * 1024);
      gload_lds16(gB + (size_t)(c * 16 + srow) * 768 + k0, (char*)Bs + c * 1024);
    }
    __syncthreads();

    const int fr = lane & 15, fk = (lane >> 4) * 8;
    f16x8 af[4], bf[4];
#pragma unroll
    for (int i = 0; i < 4; ++i)
      af[i] = *(const f16x8*)(As + (wr * 64 + i * 16 + fr) * 32 + fk);
#pragma unroll
    for (int j = 0; j < 4; ++j)
      bf[j] = *(const f16x8*)(Bs + (wc * 64 + j * 16 + fr) * 32 + fk);
#pragma unroll
    for (int i = 0; i < 4; ++i)
#pragma unroll
      for (int j = 0; j < 4; ++j)
        acc[i][j] = __builtin_amdgcn_mfma_f32_16x16x32_f16(af[i], bf[j], acc[i][j], 0, 0, 0);
  }

  const int fr = lane & 15, fq = lane >> 4;
#pragma unroll
  for (int i = 0; i < 4; ++i) {
#pragma unroll
    for (int j = 0; j < 4; ++j) {
      int gn      = bn0 + wc * 64 + j * 16 + fr;
      int gm_base = bm0 + wr * 64 + i * 16 + fq * 4;
      if (gn < 1536) {
        f16* dst = (gn < 768) ? qh : kh;
        int  col = (gn < 768) ? gn : gn - 768;
#pragma unroll
        for (int r = 0; r < 4; ++r)
          dst[(size_t)(gm_base + r) * 768 + col] = (f16)acc[i][j][r];
      } else {
        int d = gn - 1536;
        int bb = gm_base >> 12, s = gm_base & 4095;
        f16x4 h;
        h[0] = (f16)acc[i][j][0]; h[1] = (f16)acc[i][j][1];
        h[2] = (f16)acc[i][j][2]; h[3] = (f16)acc[i][j][3];
        *(f16x4*)(vth + ((size_t)bb * 768 + d) * 4096 + s) = h;
      }
    }
  }
}

// ---------------------------------------------------------------- attention
// 512 thr (8 waves), 1 WG/CU. KVSTEP=32. K double-buffered in LDS via
// global_load_lds; V single-buffered, issued at step top, consumed post-
// softmax. Raw barriers + counted vmcnt keep prefetch in flight.
// Wave w: QK^T tile (qi=w>>2, ki=(w>>1)&1) over D-half dh=w&1; PV cols w*96.
#define SM_K0   0
#define SM_K1   49152
#define SM_V    98304
#define SM_SS   147456   // float [2][32][32]
#define SM_PS   155648   // f16 [32][64B]
#define SM_M    157696
#define SM_L    157824
#define SM_F    157952
#define SM_SZ   158080

__global__ __launch_bounds__(512, 2) void attn_part(
    const f16* __restrict__ qg, const f16* __restrict__ kg,
    const f16* __restrict__ vt, f16* __restrict__ p0,
    float* __restrict__ p1, float* __restrict__ ml) {
  extern __shared__ __align__(16) char smem[];
  char*  Kb0 = smem + SM_K0;
  char*  Kb1 = smem + SM_K1;
  char*  Vb  = smem + SM_V;
  float* Ss0 = (float*)(smem + SM_SS);
  float* Ss1 = Ss0 + 1024;
  char*  Ps  = smem + SM_PS;
  float* mS  = (float*)(smem + SM_M);
  float* lS  = (float*)(smem + SM_L);
  float* fS  = (float*)(smem + SM_F);

  const int tid  = threadIdx.x;
  const int wv   = tid >> 6, lane = tid & 63;
  const int fr   = lane & 15, fq = lane >> 4;
  const int qi   = wv >> 2, ki = (wv >> 1) & 1, dh = wv & 1;

  // schedule: round 1 (u<256): qb 127..64 desc; round 2: qb 63..0 desc so the
  // earliest-freed CU (which ran the lightest heavy) takes the heaviest light.
  const int u = blockIdx.x;
  int vv = (u < 256) ? u : (u - 256);
  const int qb = ((u < 256) ? 127 : 63) - (vv >> 2);
  const int b  = (vv >> 1) & 1;
  const int c  = vv & 1;
  const int q0 = qb * 32;
  const int n  = (q0 >> 5) + 1;       // KV steps of 32 for this q-block
  const int n0 = (n + 1) >> 1;
  const int ts = c ? n0 : 0;
  const int te = c ? n : n0;

  const char* kbase = (const char*)(kg + (size_t)b * 4096 * 768);
  const char* vbase = (const char*)(vt + (size_t)b * 768 * 4096);

  // ---- Q rows for this wave's QK^T tile -> registers (48 VGPR)
  f16x8 qreg[12];
  {
    const f16* qp = qg + ((size_t)b * 4096 + q0 + qi * 16 + fr) * 768 + dh * 384 + fq * 8;
#pragma unroll
    for (int kk = 0; kk < 12; ++kk) qreg[kk] = *(const f16x8*)(qp + kk * 32);
  }

  if (tid < 32) { mS[tid] = -1e30f; lS[tid] = 0.f; }

  f32x4 acc[2][6] = {};

  // ---- prologue: stage K[ts]
  if (ts < te) {
    const char* kb = kbase + (size_t)(ts * 32) * 1536;
    char* dst = (ts & 1) ? Kb1 : Kb0;
#pragma unroll
    for (int i = 0; i < 6; ++i) {
      int lin = wv * 6144 + i * 1024 + lane * 16;
      int row = lin / 1536, cb = lin - row * 1536;
      gload_lds16(kb + (size_t)row * 1536 + (cb ^ ((row & 7) << 4)),
                  dst + wv * 6144 + i * 1024);
    }
  }
  asm volatile("s_waitcnt vmcnt(0)" ::: "memory");
  __builtin_amdgcn_s_barrier();

  for (int t = ts; t < te; ++t) {
    const int kv0 = t * 32;
    const bool pf = (t + 1 < te);

    // ---- issue V[t] (6/wave), then K[t+1] (6/wave)
    {
      const char* vb = vbase + (size_t)kv0 * 2;
#pragma unroll
      for (int i = 0; i < 6; ++i) {
        int lin = wv * 6144 + i * 1024 + lane * 16;
        int d = lin >> 6, cb = lin & 63;
        gload_lds16(vb + (size_t)d * 8192 + (cb ^ (((d >> 1) & 3) << 4)),
                    Vb + wv * 6144 + i * 1024);
      }
    }
    if (pf) {
      const char* kb = kbase + (size_t)(kv0 + 32) * 1536;
      char* dst = ((t + 1) & 1) ? Kb1 : Kb0;
#pragma unroll
      for (int i = 0; i < 6; ++i) {
        int lin = wv * 6144 + i * 1024 + lane * 16;
        int row = lin / 1536, cb = lin - row * 1536;
        gload_lds16(kb + (size_t)row * 1536 + (cb ^ ((row & 7) << 4)),
                    dst + wv * 6144 + i * 1024);
      }
    }

    // ---- QK^T: 12 MFMA over this wave's D-half
    {
      const char* kbuf = (t & 1) ? Kb1 : Kb0;
      f32x4 sc = {};
      const int krow = ki * 16 + fr;
      const int kswz = (krow & 7) << 4;
      __builtin_amdgcn_s_setprio(1);
#pragma unroll
      for (int kk = 0; kk < 12; ++kk) {
        int by = krow * 1536 + dh * 768 + kk * 64 + fq * 16;
        f16x8 kf = *(const f16x8*)(kbuf + (by ^ kswz));
        sc = __builtin_amdgcn_mfma_f32_16x16x32_f16(qreg[kk], kf, sc, 0, 0, 0);
      }
      __builtin_amdgcn_s_setprio(0);
      float* sdst = (dh ? Ss1 : Ss0) + (qi * 16 + fq * 4) * 32 + ki * 16 + fr;
#pragma unroll
      for (int r = 0; r < 4; ++r) sdst[r * 32] = sc[r];
    }
    asm volatile("s_waitcnt lgkmcnt(0)" ::: "memory");
    __builtin_amdgcn_s_barrier();                       // (1) S complete

    // ---- online softmax: row = tid>>4, 2 cols per thread
    {
      const int row = tid >> 4, sub = tid & 15;
      const int c0 = sub * 2;
      float a0 = Ss0[row * 32 + c0]     + Ss1[row * 32 + c0];
      float a1 = Ss0[row * 32 + c0 + 1] + Ss1[row * 32 + c0 + 1];
      const int grow = q0 + row;
      if (kv0 + c0     > grow) a0 = -1e30f;
      if (kv0 + c0 + 1 > grow) a1 = -1e30f;
      float mx = fmaxf(a0, a1);
      mx = fmaxf(mx, __shfl_xor(mx, 1));
      mx = fmaxf(mx, __shfl_xor(mx, 2));
      mx = fmaxf(mx, __shfl_xor(mx, 4));
      mx = fmaxf(mx, __shfl_xor(mx, 8));
      float mo = mS[row];
      float mn = fmaxf(mo, mx);
      float p0v = __expf(a0 - mn), p1v = __expf(a1 - mn);
      float sum = p0v + p1v;
      sum += __shfl_xor(sum, 1);
      sum += __shfl_xor(sum, 2);
      sum += __shfl_xor(sum, 4);
      sum += __shfl_xor(sum, 8);
      if (sub == 0) {
        float f = __expf(mo - mn);
        mS[row] = mn; fS[row] = f; lS[row] = lS[row] * f + sum;
      }
      f16x2 ph; ph[0] = (f16)p0v; ph[1] = (f16)p1v;
      int by = row * 64 + sub * 4;
      *(f16x2*)(Ps + (by ^ (((row >> 1) & 3) << 4))) = ph;
    }
    asm volatile("s_waitcnt lgkmcnt(0)" ::: "memory");
    __builtin_amdgcn_s_barrier();                       // (2) P, m/l/f complete

    // ---- rescale + PV (V arrival waited with K[t+1] still in flight)
    {
      f32x4 f0 = *(const f32x4*)(fS + fq * 4);
      f32x4 f1 = *(const f32x4*)(fS + 16 + fq * 4);
#pragma unroll
      for (int ct = 0; ct < 6; ++ct)
#pragma unroll
        for (int r = 0; r < 4; ++r) {
          acc[0][ct][r] *= f0[r];
          acc[1][ct][r] *= f1[r];
        }
      int byA0 = (fr * 64 + fq * 16) ^ (((fr >> 1) & 3) << 4);
      int rb = 16 + fr;
      int byA1 = (rb * 64 + fq * 16) ^ (((rb >> 1) & 3) << 4);
      f16x8 pa0 = *(const f16x8*)(Ps + byA0);
      f16x8 pa1 = *(const f16x8*)(Ps + byA1);
      if (pf) { asm volatile("s_waitcnt vmcnt(6)" ::: "memory"); }
      else    { asm volatile("s_waitcnt vmcnt(0)" ::: "memory"); }
      __builtin_amdgcn_s_setprio(1);
#pragma unroll
      for (int ct = 0; ct < 6; ++ct) {
        int d = wv * 96 + ct * 16 + fr;
        int by = (d * 64 + fq * 16) ^ (((d >> 1) & 3) << 4);
        f16x8 bv = *(const f16x8*)(Vb + by);
        acc[0][ct] = __builtin_amdgcn_mfma_f32_16x16x32_f16(pa0, bv, acc[0][ct], 0, 0, 0);
        acc[1][ct] = __builtin_amdgcn_mfma_f32_16x16x32_f16(pa1, bv, acc[1][ct], 0, 0, 0);
      }
      __builtin_amdgcn_s_setprio(0);
    }
    asm volatile("s_waitcnt vmcnt(0) lgkmcnt(0)" ::: "memory");
    __builtin_amdgcn_s_barrier();                       // (3) K[t+1] landed, V free
  }

  // ---- epilogue: unnormalized partial + (m,l)
  const size_t obase = (size_t)b * 4096 + q0;
  if (c == 0) {
#pragma unroll
    for (int ct = 0; ct < 6; ++ct) {
      int d = wv * 96 + ct * 16 + fr;
#pragma unroll
      for (int r = 0; r < 4; ++r) {
        p0[(obase + fq * 4 + r) * 768 + d]      = (f16)acc[0][ct][r];
        p0[(obase + 16 + fq * 4 + r) * 768 + d] = (f16)acc[1][ct][r];
      }
    }
  } else {
#pragma unroll
    for (int ct = 0; ct < 6; ++ct) {
      int d = wv * 96 + ct * 16 + fr;
#pragma unroll
      for (int r = 0; r < 4; ++r) {
        p1[(obase + fq * 4 + r) * 768 + d]      = acc[0][ct][r];
        p1[(obase + 16 + fq * 4 + r) * 768 + d] = acc[1][ct][r];
      }
    }
  }
  if (tid < 32) {
    float* mlp = ml + ((size_t)(c * 2 + b) * 4096 + q0 + tid) * 2;
    mlp[0] = mS[tid];
    mlp[1] = lS[tid];
  }
}

// ---------------------------------------------------------------- combine
__global__ __launch_bounds__(256) void attn_combine(
    const float* __restrict__ x, const f16* __restrict__ p0,
    const float* __restrict__ ml, float* __restrict__ out) {
  int i = blockIdx.x * 256 + threadIdx.x;
  int row = i / 192;
  int b = row >> 12, s = row & 4095;
  const float* m0p = ml + ((size_t)b * 4096 + s) * 2;
  const float* m1p = ml + ((size_t)(2 + b) * 4096 + s) * 2;
  float m0 = m0p[0], l0 = m0p[1];
  float m1 = m1p[0], l1 = m1p[1];
  float m  = fmaxf(m0, m1);
  float f0 = __expf(m0 - m), f1 = __expf(m1 - m);
  float inv = 1.f / (l0 * f0 + l1 * f1);
  f32x4 a1 = ((const f32x4*)out)[i];
  f16x4 a0 = ((const f16x4*)p0)[i];
  f32x4 xv = ((const f32x4*)x)[i];
  f32x4 o;
#pragma unroll
  for (int r = 0; r < 4; ++r)
    o[r] = xv[r] + ((float)a0[r] * f0 + a1[r] * f1) * inv;
  ((f32x4*)out)[i] = o;
}

// ---------------------------------------------------------------- launch
extern "C" void kernel_launch(void* const* d_in, const int* in_sizes, int n_in,
                              void* d_out, int out_size, void* d_ws, size_t ws_size,
                              hipStream_t stream) {
  const float* x  = (const float*)d_in[0];
  const float* Wp = (const float*)d_in[1];
  float* out = (float*)d_out;

  char* ws = (char*)d_ws;
  f16* x_h  = (f16*)(ws);                    // reused as p0 after proj
  f16* w_h  = (f16*)(ws + 12582912);         // reused as ml after proj
  f16* q_h  = (f16*)(ws + 16121856);
  f16* k_h  = (f16*)(ws + 28704768);
  f16* vt_h = (f16*)(ws + 41287680);

  f16*   p0 = x_h;
  float* ml = (float*)w_h;

  hipFuncSetAttribute(reinterpret_cast<const void*>(attn_part),
                      hipFuncAttributeMaxDynamicSharedMemorySize, SM_SZ);

  cvt_f32_f16<<<(M_TOK * D_MODEL) / 1024, 256, 0, stream>>>(x, x_h, (M_TOK * D_MODEL) / 4);
  cvt_f32_f16<<<(N3 * D_MODEL) / 1024, 256, 0, stream>>>(Wp, w_h, (N3 * D_MODEL) / 4);
  proj_gemm<<<dim3(64, 18), 256, 0, stream>>>(x_h, w_h, q_h, k_h, vt_h);
  attn_part<<<512, 512, SM_SZ, stream>>>(q_h, k_h, vt_h, p0, out, ml);
  attn_combine<<<(M_TOK * D_MODEL) / 1024, 256, 0, stream>>>(x, p0, ml, out);
}